// Round 5
// baseline (160.246 us; speedup 1.0000x reference)
//
#include <hip/hip_runtime.h>
#include <hip/hip_fp16.h>
#include <math.h>

#define HW    2304      // 48*48
#define NPOS  442368    // 192*48*48

typedef _Float16 f16x8 __attribute__((ext_vector_type(8)));
typedef __fp16   h16x2 __attribute__((ext_vector_type(2)));
typedef float    f32x4 __attribute__((ext_vector_type(4)));

__device__ __forceinline__ float phi_f(float z) {
    return 0.5f * (1.0f + erff(z * 0.70710678118654752f));
}
__device__ __forceinline__ unsigned short f2h(float v) {
    _Float16 h = (_Float16)v;
    return *reinterpret_cast<unsigned short*>(&h);
}
__device__ __forceinline__ unsigned int pk2(float a, float b) {
    return (unsigned int)f2h(a) | ((unsigned int)f2h(b) << 16);
}
__device__ __forceinline__ unsigned int pkrtz(float a, float b) {
    h16x2 h = __builtin_amdgcn_cvt_pkrtz(a, b);
    return *reinterpret_cast<unsigned int*>(&h);
}
__device__ __forceinline__ unsigned int bperm(int idx4, unsigned int v) {
    return (unsigned int)__builtin_amdgcn_ds_bpermute(idx4, (int)v);
}

// ---------------- prep 1/3: hyperTp transpose (948 = 79 x 12 blocks) ----------
__global__ __launch_bounds__(256) void prep_hyperTp(const float* __restrict__ hyper,
                                                    unsigned short* __restrict__ hyperTp) {
    __shared__ float s[32][33];
    const int bx = blockIdx.x;
    const int pt = bx % 79, it = bx / 79;
    const int tid = threadIdx.x;
    const int c = tid & 31, r = tid >> 5;
    const int pp = pt * 32 + c;
    const int yp = pp / 50, xp = pp % 50;
    const bool inter = (pp < 2500) && yp >= 1 && yp <= 48 && xp >= 1 && xp <= 48;
    const int src = inter ? ((yp - 1) * 48 + (xp - 1)) : 0;
#pragma unroll
    for (int i = 0; i < 4; ++i) {
        int icl = r + i * 8;
        s[icl][c] = inter ? hyper[(size_t)(it * 32 + icl) * HW + src] : 0.f;
    }
    __syncthreads();
#pragma unroll
    for (int i = 0; i < 4; ++i) {
        int pl = r + i * 8;
        int pp2 = pt * 32 + pl;
        if (pp2 < 2500)
            hyperTp[(size_t)pp2 * 384 + it * 32 + c] = f2h(s[c][pl]);
    }
}

// ---------------- prep 2/3: apack W3 -> 16-oc MFMA tiles (2592 blocks) --------
__global__ __launch_bounds__(256) void prep_apack(const float* __restrict__ W3,
                                                  unsigned short* __restrict__ apack) {
    int idx = blockIdx.x * 256 + threadIdx.x;  // 663552 total
    int j = idx & 7;
    int l = (idx >> 3) & 63;
    int rest = idx >> 9;
    int t = rest % 9; rest /= 9;
    int c = rest % 12; int T = rest / 12;
    int oc = T * 16 + (l & 15);
    int ic = c * 32 + (l >> 4) * 8 + j;
    apack[idx] = f2h(W3[((size_t)oc * 384 + ic) * 9 + t]);
}

// ---------------- prep 3/3: pk (160 blocks) + xhp (733 blocks) ----------------
__global__ __launch_bounds__(256) void prep_rest(const float* __restrict__ W1,
                                                 const float* __restrict__ Wa,
                                                 const float* __restrict__ ba,
                                                 const float* __restrict__ b1,
                                                 const float* __restrict__ Wb,
                                                 const float* __restrict__ bb,
                                                 const float* __restrict__ Wc,
                                                 const float* __restrict__ xg,
                                                 unsigned short* __restrict__ pk,
                                                 unsigned short* __restrict__ xhp) {
    const int bx = blockIdx.x;
    if (bx < 160) {                        // ---- pk: W1 masked + Wa/Wb/Wc folded
        int idx = bx * 256 + threadIdx.x;
        float v = 0.f;
        if (idx < 31744) {
            int j = idx & 7, lane = (idx >> 3) & 63, s = (idx >> 9) & 1, c = idx >> 10;
            int q = lane >> 4;
            int oc = s * 16 + (lane & 15);
            int r = 2 * c + (q >> 1), h = q & 1, kw = 8 * h + j;
            if (oc < 24 && r < 61 && kw < 11) {
                int kd = r / 11, kh = r % 11;
                int tap = kd * 121 + kh * 11 + kw;
                if (tap < 665) v = W1[oc * 1331 + tap];
            }
        } else if (idx < 33280) {
            int i2 = idx - 31744;
            int j = i2 & 7, lane = (i2 >> 3) & 63, t = i2 >> 9;
            int m = t * 16 + (lane & 15), k = (lane >> 4) * 8 + j;
            if (k < 25) v = Wa[m * 25 + k];
            else if (k == 25) {
                float s = ba[m];
                for (int c = 0; c < 24; ++c) s += Wa[m * 25 + c] * b1[c];
                v = s;
            }
        } else if (idx < 39424) {
            int i3 = idx - 33280;
            int j = i3 & 7, lane = (i3 >> 3) & 63, k2 = (i3 >> 9) & 1, s = i3 >> 10;
            int m = s * 16 + (lane & 15), ch = k2 * 32 + (lane >> 4) * 8 + j;
            if (ch < 48) v = Wb[m * 48 + ch];
            else if (ch == 48) v = bb[m];
        } else {
            int i4 = idx - 39424;
            int j = i4 & 7, lane = (i4 >> 3) & 63, k3 = i4 >> 9;
            int m = lane & 15, ch = k3 * 32 + (lane >> 4) * 8 + j;
            if (m < 9) v = Wc[m * 96 + ch];
        }
        pk[idx] = f2h(v);
    } else {                               // ---- xhp: padded fp16 volume
        int idx = (bx - 160) * 256 + threadIdx.x;   // 187456 uint2
        if (idx >= 187456) return;
        int si = idx * 4;
        int zp = si / 3712, rem = si - zp * 3712;
        int yp = rem >> 6, xp0 = rem & 63;
        float f[4];
#pragma unroll
        for (int k = 0; k < 4; ++k) {
            int xp = xp0 + k;
            bool in = zp >= 5 && zp < 197 && yp >= 5 && yp < 53 && xp >= 5 && xp < 53;
            f[k] = in ? xg[(size_t)(zp - 5) * HW + (yp - 5) * 48 + (xp - 5)] : 0.f;
        }
        *(uint2*)&xhp[si] = make_uint2(pk2(f[0], f[1]), pk2(f[2], f[3]));
    }
}

// ---------------- fused3: conv2d(in-block) + conv3d + MLP + likelihood --------
// 1728 blocks x 256 thr. Block tile: 16 d x 4 y x 4 x. Wave w <-> y row.
// LDS 32768 B: P(13312) + htile(1024) + WU(18432; hpart overlays first 4096).
// MLP weights staged global->reg (under conv3d) ->LDS (T14 async-split).
__global__ __launch_bounds__(256, 4) void fused3(const unsigned short* __restrict__ xhp,
                                                 const unsigned short* __restrict__ pk,
                                                 const unsigned short* __restrict__ hyperTp,
                                                 const unsigned short* __restrict__ apack,
                                                 const float* __restrict__ b3,
                                                 const float* __restrict__ xg,
                                                 const float* __restrict__ bc,
                                                 float* __restrict__ out) {
    __shared__ __align__(16) unsigned short P[6656];        // 13312 B: patch then acc staging
    __shared__ __align__(16) float htile[256];              //  1024 B
    __shared__ __align__(16) unsigned short WU[9216];       // 18432 B: hpart early, weights late

    const int tid = threadIdx.x, w = tid >> 6, lane = tid & 63;
    const int n = lane & 15, q = lane >> 4;
    const int bx = blockIdx.x;
    const int x0 = (bx % 12) * 4, y0 = ((bx / 12) % 12) * 4;
    const int T = bx / 144, d0 = T * 16;

    float* hpart = (float*)WU;

    // ---- stage conv3d patch: 294 rows x 2 uint4 (row = py*21+pz, 16 shorts)
#pragma unroll
    for (int k = 0; k < 3; ++k) {
        int idx = tid + k * 256;
        if (idx < 588) {
            int row = idx >> 1, half = idx & 1;
            int py = row / 21, pz = row - py * 21;
            const uint4* src = (const uint4*)(xhp + ((size_t)(d0 + pz) * 58 + (y0 + py)) * 64
                                              + x0 + half * 8);
            *(uint4*)&P[row * 16 + half * 8] = *src;
        }
    }

    // ---- conv2d partials: wave w handles ic-groups c = 3w..3w+2 (3 indep chains)
    {
        const int pp = (y0 + (n >> 2)) * 50 + x0 + (n & 3);   // pos n = (yloc, xloc)
        const size_t bbase = (size_t)pp * 384 + q * 8;
        f32x4 hc[3];
#pragma unroll
        for (int cc = 0; cc < 3; ++cc) {
            const int c = w * 3 + cc;
            const unsigned short* ap = apack + ((size_t)(T * 12 + c) * 9) * 512 + lane * 8;
            const int coff = c * 32;
            f32x4 a0 = {0.f, 0.f, 0.f, 0.f};
#pragma unroll
            for (int t = 0; t < 9; ++t) {
                f16x8 a = *(const f16x8*)(ap + t * 512);
                const int dd = (t / 3) * 50 + (t % 3);        // compile-time
                f16x8 b = *(const f16x8*)(hyperTp + bbase + (size_t)dd * 384 + coff);
                a0 = __builtin_amdgcn_mfma_f32_16x16x32_f16(a, b, a0, 0, 0, 0);
            }
            hc[cc] = a0;
        }
#pragma unroll
        for (int e = 0; e < 4; ++e)
            hpart[w * 256 + (q * 4 + e) * 16 + n] = hc[0][e] + hc[1][e] + hc[2][e];
    }
    __syncthreads();   // [B1] patch staged + hpart complete

    // ---- htile reduce: one (oc,pos) per thread; + b3 fold
    {
        const int oc = tid >> 4, pos = tid & 15;
        float h = b3[d0 + oc];
#pragma unroll
        for (int ww = 0; ww < 4; ++ww) h += hpart[ww * 256 + oc * 16 + pos];
        htile[oc * 16 + pos] = h;
    }

    // ---- issue MLP-weight loads now (1152 uint4); latency hides under conv3d
    const uint4* pkW4 = (const uint4*)(pk + 31744);
    uint4 wreg[4], wreg4;
#pragma unroll
    for (int k = 0; k < 4; ++k) wreg[k] = pkW4[tid + k * 256];
    wreg4 = (tid < 128) ? pkW4[tid + 1024] : make_uint4(0u, 0u, 0u, 0u);

    // ---- conv3d main loop, fully unrolled (round-2 proven form)
    const f32x4 zf = {0.f, 0.f, 0.f, 0.f};
    f32x4 acc[4][2];
#pragma unroll
    for (int p = 0; p < 4; ++p) { acc[p][0] = zf; acc[p][1] = zf; }

    const f16x8* Av = (const f16x8*)pk;
    const int par = q >> 1;
    const unsigned short* Pb = P + (w * 21 + n) * 16 + (q & 1) * 8;
#pragma unroll
    for (int c = 0; c < 31; ++c) {
        const int r0 = 2 * c, r1 = 2 * c + 1;
        const int o0 = ((r0 % 11) * 21 + (r0 / 11)) * 16; // compile-time
        const int o1 = ((r1 % 11) * 21 + (r1 / 11)) * 16; // compile-time
        const unsigned short* rp = Pb + (par ? o1 : o0);
        unsigned int u[6];
        *(uint4*)&u[0] = *(const uint4*)rp;
        *(uint2*)&u[4] = *(const uint2*)(rp + 8);
        f16x8 ca0 = Av[c * 128 + lane];
        f16x8 ca1 = Av[c * 128 + 64 + lane];
#pragma unroll
        for (int px = 0; px < 4; ++px) {
            unsigned int bw[4];
#pragma unroll
            for (int i = 0; i < 4; ++i) {
                if ((px & 1) == 0) bw[i] = u[(px >> 1) + i];
                else bw[i] = (u[(px >> 1) + i] >> 16) | (u[(px >> 1) + 1 + i] << 16);
            }
            f16x8 bf = *(f16x8*)bw;
            acc[px][0] = __builtin_amdgcn_mfma_f32_16x16x32_f16(ca0, bf, acc[px][0], 0, 0, 0);
            acc[px][1] = __builtin_amdgcn_mfma_f32_16x16x32_f16(ca1, bf, acc[px][1], 0, 0, 0);
        }
    }
    __syncthreads();   // [B2] patch consumed; hpart dead; P becomes acc staging

    // ---- stage acc -> P as [64 pos][104]: pos row = w*16+n, 24 oc x 4 px
#pragma unroll
    for (int px = 0; px < 4; ++px) {
        unsigned int lo = pk2(acc[px][0][0], acc[px][0][1]);
        unsigned int hi = pk2(acc[px][0][2], acc[px][0][3]);
        *(uint2*)&P[(w * 16 + n) * 104 + px * 24 + q * 4] = make_uint2(lo, hi);
        if (q < 2) {
            unsigned int l2 = pk2(acc[px][1][0], acc[px][1][1]);
            unsigned int h2 = pk2(acc[px][1][2], acc[px][1][3]);
            *(uint2*)&P[(w * 16 + n) * 104 + px * 24 + 16 + q * 4] = make_uint2(l2, h2);
        }
    }
    // ---- write staged weights into WU (overlays dead hpart)
    {
        uint4* WU4 = (uint4*)WU;
#pragma unroll
        for (int k = 0; k < 4; ++k) WU4[tid + k * 256] = wreg[k];
        if (tid < 128) WU4[tid + 1024] = wreg4;
    }
    __syncthreads();   // [B2.5] WU visible to all waves

    // ---- MLP: weights read from LDS (WU); redistribution via ds_bpermute
    const unsigned short* WaL = WU;            // 1536 shorts
    const unsigned short* WbL = WU + 1536;     // 6144 shorts
    const unsigned short* WcL = WU + 7680;     // 1536 shorts
    float bcv[4];
#pragma unroll
    for (int e = 0; e < 4; ++e) bcv[e] = (q * 4 + e < 9) ? bc[q * 4 + e] : 0.f;

    // bpermute lane indices: column group {n, n+16, n+32, n+48}, src q'' = (2q+g)&3
    const int idxg[2] = { (n + 16 * ((2 * q + 0) & 3)) * 4,
                          (n + 16 * ((2 * q + 1) & 3)) * 4 };
    const bool qlo = (q < 2);

    const f16x8 z8 = {};
    for (int px = 0; px < 4; ++px) {
        // ---- b0: 24 conv3d oc (+h, +1) from staging (wave-local)
        f16x8 b0;
        if (q < 3) {
            b0 = *(const f16x8*)&P[(w * 16 + n) * 104 + px * 24 + q * 8];
        } else {
            b0 = z8;
            b0[0] = (_Float16)htile[n * 16 + w * 4 + px];   // h feature (k=24)
            b0[1] = (_Float16)1.0f;                          // const (k=25)
        }
        // ---- layer a: 25(+h+const) -> 48, pack with relu
        unsigned int pw1[6];
#pragma unroll
        for (int s = 0; s < 3; ++s) {
            f16x8 a = *(const f16x8*)&WaL[(s * 64 + lane) * 8];
            f32x4 r1 = __builtin_amdgcn_mfma_f32_16x16x32_f16(a, b0, zf, 0, 0, 0);
            pw1[s * 2 + 0] = pkrtz(fmaxf(r1[0], 0.f), fmaxf(r1[1], 0.f));
            pw1[s * 2 + 1] = pkrtz(fmaxf(r1[2], 0.f), fmaxf(r1[3], 0.f));
        }
        // ---- a->b redistribution: 12 bpermutes (within 4-lane columns)
        unsigned int bpA[3][2][2];
#pragma unroll
        for (int s = 0; s < 3; ++s)
#pragma unroll
            for (int h = 0; h < 2; ++h) {
                bpA[s][h][0] = bperm(idxg[0], pw1[s * 2 + h]);
                bpA[s][h][1] = bperm(idxg[1], pw1[s * 2 + h]);
            }
        unsigned int bf0w[4], bf1w[4];
#pragma unroll
        for (int ww = 0; ww < 4; ++ww) {
            const int h = ww & 1, g = ww >> 1;
            bf0w[ww] = qlo ? bpA[0][h][g] : bpA[1][h][g];
            unsigned int c1 = (q == 2) ? ((ww == 0) ? 0x00003C00u : 0u) : 0u;
            bf1w[ww] = qlo ? bpA[2][h][g] : c1;
        }
        f16x8 bf0 = *(f16x8*)bf0w, bf1 = *(f16x8*)bf1w;
        // ---- layer b: 48(+const) -> 96, pack with relu
        unsigned int pw2[12];
#pragma unroll
        for (int s = 0; s < 6; ++s) {
            f16x8 a0w = *(const f16x8*)&WbL[((s * 2 + 0) * 64 + lane) * 8];
            f16x8 a1w = *(const f16x8*)&WbL[((s * 2 + 1) * 64 + lane) * 8];
            f32x4 rb = __builtin_amdgcn_mfma_f32_16x16x32_f16(a0w, bf0, zf, 0, 0, 0);
            rb = __builtin_amdgcn_mfma_f32_16x16x32_f16(a1w, bf1, rb, 0, 0, 0);
            pw2[s * 2 + 0] = pkrtz(fmaxf(rb[0], 0.f), fmaxf(rb[1], 0.f));
            pw2[s * 2 + 1] = pkrtz(fmaxf(rb[2], 0.f), fmaxf(rb[3], 0.f));
        }
        // ---- b->c redistribution (24 bpermutes) + layer c: 96 -> 9
        f32x4 rc = zf;
#pragma unroll
        for (int k3 = 0; k3 < 3; ++k3) {
            unsigned int wv[4];
#pragma unroll
            for (int ww = 0; ww < 4; ++ww) {
                const int h = ww & 1, g = ww >> 1;
                unsigned int lo_ = bperm(idxg[g], pw2[(2 * k3) * 2 + h]);
                unsigned int hi_ = bperm(idxg[g], pw2[(2 * k3 + 1) * 2 + h]);
                wv[ww] = qlo ? lo_ : hi_;
            }
            f16x8 bfc = *(f16x8*)wv;
            f16x8 aw = *(const f16x8*)&WcL[(k3 * 64 + lane) * 8];
            rc = __builtin_amdgcn_mfma_f32_16x16x32_f16(aw, bfc, rc, 0, 0, 0);
        }
        // ---- oacs: write into this px-group's (now dead) b0 segment of P
        {
            float* pr = (float*)(P + (w * 16 + n) * 104 + px * 24);
#pragma unroll
            for (int e = 0; e < 4; ++e) {
                const int row = q * 4 + e;
                if (row < 9) pr[row] = rc[e] + bcv[e];
            }
        }
    }

    // ---- likelihood: all 64 lanes, lane l -> pos (d = d0 + l>>2, y = y0+w, x = x0 + (l&3))
    {
        const float* pr = (const float*)(P + (w * 16 + (lane >> 2)) * 104 + (lane & 3) * 24);
        f32x4 oA = *(const f32x4*)pr;
        f32x4 oB = *(const f32x4*)(pr + 4);
        float o8 = pr[8];
        const int gp = (d0 + (lane >> 2)) * HW + (y0 + w) * 48 + x0 + (lane & 3);
        const float xv = xg[gp];
        float m = fmaxf(oB[2], fmaxf(oB[3], o8));
        float e0 = expf(oB[2] - m), e1 = expf(oB[3] - m), e2 = expf(o8 - m);
        float inv_es = 1.0f / (e0 + e1 + e2);
        float mu0 = oA[0], mu1 = oA[1], mu2 = oA[2];
        float s0 = oA[3], s1 = oB[0], s2 = oB[1];
        float p = 0.f;
#pragma unroll
        for (int jj = 0; jj < 3; ++jj) {
            float mu = (jj == 0) ? mu0 : (jj == 1) ? mu1 : mu2;
            float sc = (jj == 0) ? s0 : (jj == 1) ? s1 : s2;
            sc = (sc == 0.0f) ? 1e-9f : sc;
            sc = fabsf(sc);
            float a = phi_f((xv + 0.5f - mu) / sc);
            float b = phi_f((xv - 0.5f - mu) / sc);
            float lik = fabsf(a - b);
            float wgt = ((jj == 0) ? e0 : (jj == 1) ? e1 : e2) * inv_es;
            p = fmaf(wgt, lik, p);
        }
        out[gp] = p;
        out[NPOS + (size_t)0 * NPOS + gp] = mu0;
        out[NPOS + (size_t)1 * NPOS + gp] = mu1;
        out[NPOS + (size_t)2 * NPOS + gp] = mu2;
        out[NPOS + (size_t)3 * NPOS + gp] = s0;
        out[NPOS + (size_t)4 * NPOS + gp] = s1;
        out[NPOS + (size_t)5 * NPOS + gp] = s2;
        out[NPOS + (size_t)6 * NPOS + gp] = oB[2];
        out[NPOS + (size_t)7 * NPOS + gp] = oB[3];
        out[NPOS + (size_t)8 * NPOS + gp] = o8;
    }
}

extern "C" void kernel_launch(void* const* d_in, const int* in_sizes, int n_in,
                              void* d_out, int out_size, void* d_ws, size_t ws_size,
                              hipStream_t stream) {
    const float* x     = (const float*)d_in[0];
    const float* hyper = (const float*)d_in[1];
    const float* W3    = (const float*)d_in[2];
    const float* b3    = (const float*)d_in[3];
    const float* W1    = (const float*)d_in[4];
    const float* b1    = (const float*)d_in[5];
    const float* Wa    = (const float*)d_in[6];
    const float* ba    = (const float*)d_in[7];
    const float* Wb    = (const float*)d_in[8];
    const float* bb    = (const float*)d_in[9];
    const float* Wc    = (const float*)d_in[10];
    const float* bc    = (const float*)d_in[11];
    float* out = (float*)d_out;

    unsigned short* hyperTp = (unsigned short*)d_ws;           // 960000 f16
    unsigned short* apack   = hyperTp + 960000;                // 663552 f16
    unsigned short* pk      = apack + 663552;                  // 40960 f16
    unsigned short* xhp     = pk + 40960;                      // 749824 f16 (padded x)

    prep_hyperTp<<<948, 256, 0, stream>>>(hyper, hyperTp);
    prep_apack<<<2592, 256, 0, stream>>>(W3, apack);
    prep_rest<<<893, 256, 0, stream>>>(W1, Wa, ba, b1, Wb, bb, Wc, x, pk, xhp);
    fused3<<<1728, 256, 0, stream>>>(xhp, pk, hyperTp, apack, b3, x, bc, out);
}

// Round 6
// 154.174 us; speedup vs baseline: 1.0394x; 1.0394x over previous
//
#include <hip/hip_runtime.h>
#include <hip/hip_fp16.h>
#include <math.h>

#define HW    2304      // 48*48
#define NPOS  442368    // 192*48*48

typedef _Float16 f16x8 __attribute__((ext_vector_type(8)));
typedef __fp16   h16x2 __attribute__((ext_vector_type(2)));
typedef float    f32x4 __attribute__((ext_vector_type(4)));

__device__ __forceinline__ float phi_f(float z) {
    return 0.5f * (1.0f + erff(z * 0.70710678118654752f));
}
__device__ __forceinline__ unsigned short f2h(float v) {
    _Float16 h = (_Float16)v;
    return *reinterpret_cast<unsigned short*>(&h);
}
__device__ __forceinline__ unsigned int pk2(float a, float b) {
    return (unsigned int)f2h(a) | ((unsigned int)f2h(b) << 16);
}
__device__ __forceinline__ unsigned int pkrtz(float a, float b) {
    h16x2 h = __builtin_amdgcn_cvt_pkrtz(a, b);
    return *reinterpret_cast<unsigned int*>(&h);
}
__device__ __forceinline__ unsigned int bperm(int idx4, unsigned int v) {
    return (unsigned int)__builtin_amdgcn_ds_bpermute(idx4, (int)v);
}
// async global->LDS, 16 B per lane; LDS dest = uniform base + lane*16
__device__ __forceinline__ void gll16(const unsigned short* g, unsigned short* l) {
    __builtin_amdgcn_global_load_lds(
        (const __attribute__((address_space(1))) unsigned int*)g,
        (__attribute__((address_space(3))) unsigned int*)l, 16, 0, 0);
}

// ---------------- prep_all: hyperTp transpose + apack + pk + xhp ---------------
// blocks [0,948): hyperTp ; [948,3540): apack ; [3540,3700): pk ; rest: xhp
__global__ __launch_bounds__(256) void prep_all(const float* __restrict__ hyper,
                                                const float* __restrict__ W3,
                                                const float* __restrict__ W1,
                                                const float* __restrict__ Wa,
                                                const float* __restrict__ ba,
                                                const float* __restrict__ b1,
                                                const float* __restrict__ Wb,
                                                const float* __restrict__ bb,
                                                const float* __restrict__ Wc,
                                                const float* __restrict__ xg,
                                                unsigned short* __restrict__ hyperTp,
                                                unsigned short* __restrict__ apack,
                                                unsigned short* __restrict__ pk,
                                                unsigned short* __restrict__ xhp) {
    const int bx = blockIdx.x;
    if (bx < 948) {                        // ---- hyperTp (948 = 79 x 12)
        __shared__ float s[32][33];
        const int pt = bx % 79, it = bx / 79;
        const int tid = threadIdx.x;
        const int c = tid & 31, r = tid >> 5;
        const int pp = pt * 32 + c;
        const int yp = pp / 50, xp = pp % 50;
        const bool inter = (pp < 2500) && yp >= 1 && yp <= 48 && xp >= 1 && xp <= 48;
        const int src = inter ? ((yp - 1) * 48 + (xp - 1)) : 0;
#pragma unroll
        for (int i = 0; i < 4; ++i) {
            int icl = r + i * 8;
            s[icl][c] = inter ? hyper[(size_t)(it * 32 + icl) * HW + src] : 0.f;
        }
        __syncthreads();
#pragma unroll
        for (int i = 0; i < 4; ++i) {
            int pl = r + i * 8;
            int pp2 = pt * 32 + pl;
            if (pp2 < 2500)
                hyperTp[(size_t)pp2 * 384 + it * 32 + c] = f2h(s[c][pl]);
        }
    } else if (bx < 3540) {                // ---- apack: W3 -> 16-oc MFMA tiles
        int idx = (bx - 948) * 256 + threadIdx.x;  // 663552 total
        int j = idx & 7;
        int l = (idx >> 3) & 63;
        int rest = idx >> 9;
        int t = rest % 9; rest /= 9;
        int c = rest % 12; int T = rest / 12;
        int oc = T * 16 + (l & 15);
        int ic = c * 32 + (l >> 4) * 8 + j;
        apack[idx] = f2h(W3[((size_t)oc * 384 + ic) * 9 + t]);
    } else if (bx < 3700) {                // ---- pk: W1 masked + Wa/Wb/Wc folded
        int idx = (bx - 3540) * 256 + threadIdx.x;
        if (idx >= 40960) return;
        float v = 0.f;
        if (idx < 31744) {
            int j = idx & 7, lane = (idx >> 3) & 63, s = (idx >> 9) & 1, c = idx >> 10;
            int q = lane >> 4;
            int oc = s * 16 + (lane & 15);
            int r = 2 * c + (q >> 1), h = q & 1, kw = 8 * h + j;
            if (oc < 24 && r < 61 && kw < 11) {
                int kd = r / 11, kh = r % 11;
                int tap = kd * 121 + kh * 11 + kw;
                if (tap < 665) v = W1[oc * 1331 + tap];
            }
        } else if (idx < 33280) {
            int i2 = idx - 31744;
            int j = i2 & 7, lane = (i2 >> 3) & 63, t = i2 >> 9;
            int m = t * 16 + (lane & 15), k = (lane >> 4) * 8 + j;
            if (k < 25) v = Wa[m * 25 + k];
            else if (k == 25) {
                float s = ba[m];
                for (int c = 0; c < 24; ++c) s += Wa[m * 25 + c] * b1[c];
                v = s;
            }
        } else if (idx < 39424) {
            int i3 = idx - 33280;
            int j = i3 & 7, lane = (i3 >> 3) & 63, k2 = (i3 >> 9) & 1, s = i3 >> 10;
            int m = s * 16 + (lane & 15), ch = k2 * 32 + (lane >> 4) * 8 + j;
            if (ch < 48) v = Wb[m * 48 + ch];
            else if (ch == 48) v = bb[m];
        } else {
            int i4 = idx - 39424;
            int j = i4 & 7, lane = (i4 >> 3) & 63, k3 = i4 >> 9;
            int m = lane & 15, ch = k3 * 32 + (lane >> 4) * 8 + j;
            if (m < 9) v = Wc[m * 96 + ch];
        }
        pk[idx] = f2h(v);
    } else {                               // ---- xhp: padded fp16 volume
        int idx = (bx - 3700) * 256 + threadIdx.x;   // 187456 uint2
        if (idx >= 187456) return;
        int si = idx * 4;
        int zp = si / 3712, rem = si - zp * 3712;
        int yp = rem >> 6, xp0 = rem & 63;
        float f[4];
#pragma unroll
        for (int k = 0; k < 4; ++k) {
            int xp = xp0 + k;
            bool in = zp >= 5 && zp < 197 && yp >= 5 && yp < 53 && xp >= 5 && xp < 53;
            f[k] = in ? xg[(size_t)(zp - 5) * HW + (yp - 5) * 48 + (xp - 5)] : 0.f;
        }
        *(uint2*)&xhp[si] = make_uint2(pk2(f[0], f[1]), pk2(f[2], f[3]));
    }
}

// ---------------- fused3: conv2d(in-block) + conv3d + MLP + likelihood --------
// 1728 blocks x 256 thr. Block tile: 16 d x 4 y x 4 x. Wave w <-> y row.
// LDS 36864 B: P(13312) + htile(1024) + hpart(4096) + WU(18432).
// MLP weights staged global->LDS via global_load_lds (zero VGPR, no scratch).
__global__ __launch_bounds__(256, 4) void fused3(const unsigned short* __restrict__ xhp,
                                                 const unsigned short* __restrict__ pk,
                                                 const unsigned short* __restrict__ hyperTp,
                                                 const unsigned short* __restrict__ apack,
                                                 const float* __restrict__ b3,
                                                 const float* __restrict__ xg,
                                                 const float* __restrict__ bc,
                                                 float* __restrict__ out) {
    __shared__ __align__(16) unsigned short P[6656];        // 13312 B: patch then acc staging
    __shared__ __align__(16) float htile[256];              //  1024 B
    __shared__ __align__(16) float hpart[1024];             //  4096 B
    __shared__ __align__(16) unsigned short WU[9216];       // 18432 B: MLP weights

    const int tid = threadIdx.x, w = tid >> 6, lane = tid & 63;
    const int n = lane & 15, q = lane >> 4;
    const int bx = blockIdx.x;
    const int x0 = (bx % 12) * 4, y0 = ((bx / 12) % 12) * 4;
    const int T = bx / 144, d0 = T * 16;

    // ---- stage MLP weights (18 x 1024 B) via async global->LDS; done by [B1]
#pragma unroll
    for (int k = 0; k < 5; ++k) {
        int s = w + k * 4;
        if (s < 18)
            gll16(pk + 31744 + s * 512 + lane * 8, WU + s * 512);
    }

    // ---- stage conv3d patch: 294 rows x 2 uint4 (row = py*21+pz, 16 shorts)
#pragma unroll
    for (int k = 0; k < 3; ++k) {
        int idx = tid + k * 256;
        if (idx < 588) {
            int row = idx >> 1, half = idx & 1;
            int py = row / 21, pz = row - py * 21;
            const uint4* src = (const uint4*)(xhp + ((size_t)(d0 + pz) * 58 + (y0 + py)) * 64
                                              + x0 + half * 8);
            *(uint4*)&P[row * 16 + half * 8] = *src;
        }
    }

    // ---- conv2d partials: wave w handles ic-groups c = 3w..3w+2 (3 indep chains)
    {
        const int pp = (y0 + (n >> 2)) * 50 + x0 + (n & 3);   // pos n = (yloc, xloc)
        const size_t bbase = (size_t)pp * 384 + q * 8;
        f32x4 hc[3];
#pragma unroll
        for (int cc = 0; cc < 3; ++cc) {
            const int c = w * 3 + cc;
            const unsigned short* ap = apack + ((size_t)(T * 12 + c) * 9) * 512 + lane * 8;
            const int coff = c * 32;
            f32x4 a0 = {0.f, 0.f, 0.f, 0.f};
#pragma unroll
            for (int t = 0; t < 9; ++t) {
                f16x8 a = *(const f16x8*)(ap + t * 512);
                const int dd = (t / 3) * 50 + (t % 3);        // compile-time
                f16x8 b = *(const f16x8*)(hyperTp + bbase + (size_t)dd * 384 + coff);
                a0 = __builtin_amdgcn_mfma_f32_16x16x32_f16(a, b, a0, 0, 0, 0);
            }
            hc[cc] = a0;
        }
#pragma unroll
        for (int e = 0; e < 4; ++e)
            hpart[w * 256 + (q * 4 + e) * 16 + n] = hc[0][e] + hc[1][e] + hc[2][e];
    }
    __syncthreads();   // [B1] patch staged + hpart complete + weights landed

    // ---- htile reduce: one (oc,pos) per thread; + b3 fold
    {
        const int oc = tid >> 4, pos = tid & 15;
        float h = b3[d0 + oc];
#pragma unroll
        for (int ww = 0; ww < 4; ++ww) h += hpart[ww * 256 + oc * 16 + pos];
        htile[oc * 16 + pos] = h;
    }

    // ---- conv3d main loop, fully unrolled (round-2 proven form)
    const f32x4 zf = {0.f, 0.f, 0.f, 0.f};
    f32x4 acc[4][2];
#pragma unroll
    for (int p = 0; p < 4; ++p) { acc[p][0] = zf; acc[p][1] = zf; }

    const f16x8* Av = (const f16x8*)pk;
    const int par = q >> 1;
    const unsigned short* Pb = P + (w * 21 + n) * 16 + (q & 1) * 8;
#pragma unroll
    for (int c = 0; c < 31; ++c) {
        const int r0 = 2 * c, r1 = 2 * c + 1;
        const int o0 = ((r0 % 11) * 21 + (r0 / 11)) * 16; // compile-time
        const int o1 = ((r1 % 11) * 21 + (r1 / 11)) * 16; // compile-time
        const unsigned short* rp = Pb + (par ? o1 : o0);
        unsigned int u[6];
        *(uint4*)&u[0] = *(const uint4*)rp;
        *(uint2*)&u[4] = *(const uint2*)(rp + 8);
        f16x8 ca0 = Av[c * 128 + lane];
        f16x8 ca1 = Av[c * 128 + 64 + lane];
#pragma unroll
        for (int px = 0; px < 4; ++px) {
            unsigned int bw[4];
#pragma unroll
            for (int i = 0; i < 4; ++i) {
                if ((px & 1) == 0) bw[i] = u[(px >> 1) + i];
                else bw[i] = (u[(px >> 1) + i] >> 16) | (u[(px >> 1) + 1 + i] << 16);
            }
            f16x8 bf = *(f16x8*)bw;
            acc[px][0] = __builtin_amdgcn_mfma_f32_16x16x32_f16(ca0, bf, acc[px][0], 0, 0, 0);
            acc[px][1] = __builtin_amdgcn_mfma_f32_16x16x32_f16(ca1, bf, acc[px][1], 0, 0, 0);
        }
    }
    __syncthreads();   // [B2] patch consumed; P becomes acc staging

    // ---- stage acc -> P as [64 pos][104]: pos row = w*16+n, 24 oc x 4 px
#pragma unroll
    for (int px = 0; px < 4; ++px) {
        unsigned int lo = pk2(acc[px][0][0], acc[px][0][1]);
        unsigned int hi = pk2(acc[px][0][2], acc[px][0][3]);
        *(uint2*)&P[(w * 16 + n) * 104 + px * 24 + q * 4] = make_uint2(lo, hi);
        if (q < 2) {
            unsigned int l2 = pk2(acc[px][1][0], acc[px][1][1]);
            unsigned int h2 = pk2(acc[px][1][2], acc[px][1][3]);
            *(uint2*)&P[(w * 16 + n) * 104 + px * 24 + 16 + q * 4] = make_uint2(l2, h2);
        }
    }
    // everything below is wave-local: LDS (b0/oacs/WU) + ds_bpermute, no barriers

    // ---- MLP: weights read from LDS (WU); redistribution via ds_bpermute
    const unsigned short* WaL = WU;            // 1536 shorts
    const unsigned short* WbL = WU + 1536;     // 6144 shorts
    const unsigned short* WcL = WU + 7680;     // 1536 shorts
    float bcv[4];
#pragma unroll
    for (int e = 0; e < 4; ++e) bcv[e] = (q * 4 + e < 9) ? bc[q * 4 + e] : 0.f;

    // bpermute lane indices: column group {n, n+16, n+32, n+48}, src q'' = (2q+g)&3
    const int idxg[2] = { (n + 16 * ((2 * q + 0) & 3)) * 4,
                          (n + 16 * ((2 * q + 1) & 3)) * 4 };
    const bool qlo = (q < 2);

    const f16x8 z8 = {};
    for (int px = 0; px < 4; ++px) {
        // ---- b0: 24 conv3d oc (+h, +1) from staging (wave-local)
        f16x8 b0;
        if (q < 3) {
            b0 = *(const f16x8*)&P[(w * 16 + n) * 104 + px * 24 + q * 8];
        } else {
            b0 = z8;
            b0[0] = (_Float16)htile[n * 16 + w * 4 + px];   // h feature (k=24)
            b0[1] = (_Float16)1.0f;                          // const (k=25)
        }
        // ---- layer a: 25(+h+const) -> 48, pack with relu
        unsigned int pw1[6];
#pragma unroll
        for (int s = 0; s < 3; ++s) {
            f16x8 a = *(const f16x8*)&WaL[(s * 64 + lane) * 8];
            f32x4 r1 = __builtin_amdgcn_mfma_f32_16x16x32_f16(a, b0, zf, 0, 0, 0);
            pw1[s * 2 + 0] = pkrtz(fmaxf(r1[0], 0.f), fmaxf(r1[1], 0.f));
            pw1[s * 2 + 1] = pkrtz(fmaxf(r1[2], 0.f), fmaxf(r1[3], 0.f));
        }
        // ---- a->b redistribution: 12 bpermutes (within 4-lane columns)
        unsigned int bpA[3][2][2];
#pragma unroll
        for (int s = 0; s < 3; ++s)
#pragma unroll
            for (int h = 0; h < 2; ++h) {
                bpA[s][h][0] = bperm(idxg[0], pw1[s * 2 + h]);
                bpA[s][h][1] = bperm(idxg[1], pw1[s * 2 + h]);
            }
        unsigned int bf0w[4], bf1w[4];
#pragma unroll
        for (int ww = 0; ww < 4; ++ww) {
            const int h = ww & 1, g = ww >> 1;
            bf0w[ww] = qlo ? bpA[0][h][g] : bpA[1][h][g];
            unsigned int c1 = (q == 2) ? ((ww == 0) ? 0x00003C00u : 0u) : 0u;
            bf1w[ww] = qlo ? bpA[2][h][g] : c1;
        }
        f16x8 bf0 = *(f16x8*)bf0w, bf1 = *(f16x8*)bf1w;
        // ---- layer b: 48(+const) -> 96, pack with relu
        unsigned int pw2[12];
#pragma unroll
        for (int s = 0; s < 6; ++s) {
            f16x8 a0w = *(const f16x8*)&WbL[((s * 2 + 0) * 64 + lane) * 8];
            f16x8 a1w = *(const f16x8*)&WbL[((s * 2 + 1) * 64 + lane) * 8];
            f32x4 rb = __builtin_amdgcn_mfma_f32_16x16x32_f16(a0w, bf0, zf, 0, 0, 0);
            rb = __builtin_amdgcn_mfma_f32_16x16x32_f16(a1w, bf1, rb, 0, 0, 0);
            pw2[s * 2 + 0] = pkrtz(fmaxf(rb[0], 0.f), fmaxf(rb[1], 0.f));
            pw2[s * 2 + 1] = pkrtz(fmaxf(rb[2], 0.f), fmaxf(rb[3], 0.f));
        }
        // ---- b->c redistribution (24 bpermutes) + layer c: 96 -> 9
        f32x4 rc = zf;
#pragma unroll
        for (int k3 = 0; k3 < 3; ++k3) {
            unsigned int wv[4];
#pragma unroll
            for (int ww = 0; ww < 4; ++ww) {
                const int h = ww & 1, g = ww >> 1;
                unsigned int lo_ = bperm(idxg[g], pw2[(2 * k3) * 2 + h]);
                unsigned int hi_ = bperm(idxg[g], pw2[(2 * k3 + 1) * 2 + h]);
                wv[ww] = qlo ? lo_ : hi_;
            }
            f16x8 bfc = *(f16x8*)wv;
            f16x8 aw = *(const f16x8*)&WcL[(k3 * 64 + lane) * 8];
            rc = __builtin_amdgcn_mfma_f32_16x16x32_f16(aw, bfc, rc, 0, 0, 0);
        }
        // ---- oacs: write into this px-group's (now dead) b0 segment of P
        {
            float* pr = (float*)(P + (w * 16 + n) * 104 + px * 24);
#pragma unroll
            for (int e = 0; e < 4; ++e) {
                const int row = q * 4 + e;
                if (row < 9) pr[row] = rc[e] + bcv[e];
            }
        }
    }

    // ---- likelihood: all 64 lanes, lane l -> pos (d = d0 + l>>2, y = y0+w, x = x0 + (l&3))
    {
        const float* pr = (const float*)(P + (w * 16 + (lane >> 2)) * 104 + (lane & 3) * 24);
        f32x4 oA = *(const f32x4*)pr;
        f32x4 oB = *(const f32x4*)(pr + 4);
        float o8 = pr[8];
        const int gp = (d0 + (lane >> 2)) * HW + (y0 + w) * 48 + x0 + (lane & 3);
        const float xv = xg[gp];
        float m = fmaxf(oB[2], fmaxf(oB[3], o8));
        float e0 = expf(oB[2] - m), e1 = expf(oB[3] - m), e2 = expf(o8 - m);
        float inv_es = 1.0f / (e0 + e1 + e2);
        float mu0 = oA[0], mu1 = oA[1], mu2 = oA[2];
        float s0 = oA[3], s1 = oB[0], s2 = oB[1];
        float p = 0.f;
#pragma unroll
        for (int jj = 0; jj < 3; ++jj) {
            float mu = (jj == 0) ? mu0 : (jj == 1) ? mu1 : mu2;
            float sc = (jj == 0) ? s0 : (jj == 1) ? s1 : s2;
            sc = (sc == 0.0f) ? 1e-9f : sc;
            sc = fabsf(sc);
            float a = phi_f((xv + 0.5f - mu) / sc);
            float b = phi_f((xv - 0.5f - mu) / sc);
            float lik = fabsf(a - b);
            float wgt = ((jj == 0) ? e0 : (jj == 1) ? e1 : e2) * inv_es;
            p = fmaf(wgt, lik, p);
        }
        out[gp] = p;
        out[NPOS + (size_t)0 * NPOS + gp] = mu0;
        out[NPOS + (size_t)1 * NPOS + gp] = mu1;
        out[NPOS + (size_t)2 * NPOS + gp] = mu2;
        out[NPOS + (size_t)3 * NPOS + gp] = s0;
        out[NPOS + (size_t)4 * NPOS + gp] = s1;
        out[NPOS + (size_t)5 * NPOS + gp] = s2;
        out[NPOS + (size_t)6 * NPOS + gp] = oB[2];
        out[NPOS + (size_t)7 * NPOS + gp] = oB[3];
        out[NPOS + (size_t)8 * NPOS + gp] = o8;
    }
}

extern "C" void kernel_launch(void* const* d_in, const int* in_sizes, int n_in,
                              void* d_out, int out_size, void* d_ws, size_t ws_size,
                              hipStream_t stream) {
    const float* x     = (const float*)d_in[0];
    const float* hyper = (const float*)d_in[1];
    const float* W3    = (const float*)d_in[2];
    const float* b3    = (const float*)d_in[3];
    const float* W1    = (const float*)d_in[4];
    const float* b1    = (const float*)d_in[5];
    const float* Wa    = (const float*)d_in[6];
    const float* ba    = (const float*)d_in[7];
    const float* Wb    = (const float*)d_in[8];
    const float* bb    = (const float*)d_in[9];
    const float* Wc    = (const float*)d_in[10];
    const float* bc    = (const float*)d_in[11];
    float* out = (float*)d_out;

    unsigned short* hyperTp = (unsigned short*)d_ws;           // 960000 f16
    unsigned short* apack   = hyperTp + 960000;                // 663552 f16
    unsigned short* pk      = apack + 663552;                  // 40960 f16
    unsigned short* xhp     = pk + 40960;                      // 749824 f16 (padded x)

    prep_all<<<4433, 256, 0, stream>>>(hyper, W3, W1, Wa, ba, b1, Wb, bb, Wc, x,
                                       hyperTp, apack, pk, xhp);
    fused3<<<1728, 256, 0, stream>>>(xhp, pk, hyperTp, apack, b3, x, bc, out);
}

// Round 7
// 149.067 us; speedup vs baseline: 1.0750x; 1.0343x over previous
//
#include <hip/hip_runtime.h>
#include <hip/hip_fp16.h>
#include <math.h>

#define HW    2304      // 48*48
#define NPOS  442368    // 192*48*48

typedef _Float16 f16x8 __attribute__((ext_vector_type(8)));
typedef __fp16   h16x2 __attribute__((ext_vector_type(2)));
typedef float    f32x4 __attribute__((ext_vector_type(4)));

__device__ __forceinline__ float phi_f(float z) {
    return 0.5f * (1.0f + erff(z * 0.70710678118654752f));
}
__device__ __forceinline__ unsigned short f2h(float v) {
    _Float16 h = (_Float16)v;
    return *reinterpret_cast<unsigned short*>(&h);
}
__device__ __forceinline__ unsigned int pk2(float a, float b) {
    return (unsigned int)f2h(a) | ((unsigned int)f2h(b) << 16);
}
__device__ __forceinline__ unsigned int pkrtz(float a, float b) {
    h16x2 h = __builtin_amdgcn_cvt_pkrtz(a, b);
    return *reinterpret_cast<unsigned int*>(&h);
}
__device__ __forceinline__ unsigned int bperm(int idx4, unsigned int v) {
    return (unsigned int)__builtin_amdgcn_ds_bpermute(idx4, (int)v);
}
// async global->LDS, 16 B per lane; LDS dest = wave-uniform base + lane*16
__device__ __forceinline__ void gll16(const unsigned short* g, unsigned short* l) {
    __builtin_amdgcn_global_load_lds(
        (const __attribute__((address_space(1))) unsigned int*)g,
        (__attribute__((address_space(3))) unsigned int*)l, 16, 0, 0);
}

// ---------------- prep_all ----------------------------------------------------
// blocks [0,948): hyperTp ; [948,1092): apack (tiled) ; [1092,1252): pk ; rest xhp
__global__ __launch_bounds__(256) void prep_all(const float* __restrict__ hyper,
                                                const float* __restrict__ W3,
                                                const float* __restrict__ W1,
                                                const float* __restrict__ Wa,
                                                const float* __restrict__ ba,
                                                const float* __restrict__ b1,
                                                const float* __restrict__ Wb,
                                                const float* __restrict__ bb,
                                                const float* __restrict__ Wc,
                                                const float* __restrict__ xg,
                                                unsigned short* __restrict__ hyperTp,
                                                unsigned short* __restrict__ apack,
                                                unsigned short* __restrict__ pk,
                                                unsigned short* __restrict__ xhp) {
    const int bx = blockIdx.x;
    if (bx < 948) {                        // ---- hyperTp (948 = 79 x 12)
        __shared__ float s[32][33];
        const int pt = bx % 79, it = bx / 79;
        const int tid = threadIdx.x;
        const int c = tid & 31, r = tid >> 5;
        const int pp = pt * 32 + c;
        const int yp = pp / 50, xp = pp % 50;
        const bool inter = (pp < 2500) && yp >= 1 && yp <= 48 && xp >= 1 && xp <= 48;
        const int src = inter ? ((yp - 1) * 48 + (xp - 1)) : 0;
#pragma unroll
        for (int i = 0; i < 4; ++i) {
            int icl = r + i * 8;
            s[icl][c] = inter ? hyper[(size_t)(it * 32 + icl) * HW + src] : 0.f;
        }
        __syncthreads();
#pragma unroll
        for (int i = 0; i < 4; ++i) {
            int pl = r + i * 8;
            int pp2 = pt * 32 + pl;
            if (pp2 < 2500)
                hyperTp[(size_t)pp2 * 384 + it * 32 + c] = f2h(s[c][pl]);
        }
    } else if (bx < 1092) {                // ---- apack: one block per (T,c) tile
        __shared__ float ws[16 * 288];     // 18432 B: oc-row x (ic*9+t) slice
        const int b = bx - 948;            // 0..143
        const int T = b / 12, c = b % 12;
        const int tid = threadIdx.x;
        // coalesced stage: 16 oc x 288 floats (ic in [c*32,c*32+32), all 9 taps)
#pragma unroll
        for (int i = 0; i < 18; ++i) {
            int fi = tid + i * 256;        // 0..4607
            int row = fi / 288, col = fi - row * 288;
            ws[row * 288 + col] = W3[(size_t)(T * 16 + row) * 3456 + c * 288 + col];
        }
        __syncthreads();
        // coalesced write: apack[(T*12+c)*4608 + o], o = t*512 + l*8 + j
        unsigned short* ap = apack + (size_t)(T * 12 + c) * 4608;
#pragma unroll
        for (int i = 0; i < 18; ++i) {
            int o = tid + i * 256;
            int j = o & 7, l = (o >> 3) & 63, t = o >> 9;
            int ocl = l & 15, icl = (l >> 4) * 8 + j;
            ap[o] = f2h(ws[ocl * 288 + icl * 9 + t]);
        }
    } else if (bx < 1252) {                // ---- pk: W1 masked + Wa/Wb/Wc folded
        int idx = (bx - 1092) * 256 + threadIdx.x;
        if (idx >= 40960) return;
        float v = 0.f;
        if (idx < 31744) {
            int j = idx & 7, lane = (idx >> 3) & 63, s = (idx >> 9) & 1, c = idx >> 10;
            int q = lane >> 4;
            int oc = s * 16 + (lane & 15);
            int r = 2 * c + (q >> 1), h = q & 1, kw = 8 * h + j;
            if (oc < 24 && r < 61 && kw < 11) {
                int kd = r / 11, kh = r % 11;
                int tap = kd * 121 + kh * 11 + kw;
                if (tap < 665) v = W1[oc * 1331 + tap];
            }
        } else if (idx < 33280) {
            int i2 = idx - 31744;
            int j = i2 & 7, lane = (i2 >> 3) & 63, t = i2 >> 9;
            int m = t * 16 + (lane & 15), k = (lane >> 4) * 8 + j;
            if (k < 25) v = Wa[m * 25 + k];
            else if (k == 25) {
                float s = ba[m];
                for (int c = 0; c < 24; ++c) s += Wa[m * 25 + c] * b1[c];
                v = s;
            }
        } else if (idx < 39424) {
            int i3 = idx - 33280;
            int j = i3 & 7, lane = (i3 >> 3) & 63, k2 = (i3 >> 9) & 1, s = i3 >> 10;
            int m = s * 16 + (lane & 15), ch = k2 * 32 + (lane >> 4) * 8 + j;
            if (ch < 48) v = Wb[m * 48 + ch];
            else if (ch == 48) v = bb[m];
        } else {
            int i4 = idx - 39424;
            int j = i4 & 7, lane = (i4 >> 3) & 63, k3 = i4 >> 9;
            int m = lane & 15, ch = k3 * 32 + (lane >> 4) * 8 + j;
            if (m < 9) v = Wc[m * 96 + ch];
        }
        pk[idx] = f2h(v);
    } else {                               // ---- xhp: padded fp16 volume
        int idx = (bx - 1252) * 256 + threadIdx.x;   // 187456 uint2
        if (idx >= 187456) return;
        int si = idx * 4;
        int zp = si / 3712, rem = si - zp * 3712;
        int yp = rem >> 6, xp0 = rem & 63;
        float f[4];
#pragma unroll
        for (int k = 0; k < 4; ++k) {
            int xp = xp0 + k;
            bool in = zp >= 5 && zp < 197 && yp >= 5 && yp < 53 && xp >= 5 && xp < 53;
            f[k] = in ? xg[(size_t)(zp - 5) * HW + (yp - 5) * 48 + (xp - 5)] : 0.f;
        }
        *(uint2*)&xhp[si] = make_uint2(pk2(f[0], f[1]), pk2(f[2], f[3]));
    }
}

// ---------------- fused3: conv2d(in-block) + conv3d + MLP + likelihood --------
// 1728 blocks x 256 thr. Block tile: 16 d x 4 y x 4 x. Wave w <-> y row.
// LDS 36864 B: P(13312) + htile(1024) + hpart(4096) + WU(18432).
// Patch + MLP weights staged via global_load_lds (no VGPR round-trip).
__global__ __launch_bounds__(256, 4) void fused3(const unsigned short* __restrict__ xhp,
                                                 const unsigned short* __restrict__ pk,
                                                 const unsigned short* __restrict__ hyperTp,
                                                 const unsigned short* __restrict__ apack,
                                                 const float* __restrict__ b3,
                                                 const float* __restrict__ xg,
                                                 const float* __restrict__ bc,
                                                 float* __restrict__ out) {
    __shared__ __align__(16) unsigned short P[6656];        // 13312 B: patch then acc staging
    __shared__ __align__(16) float htile[256];              //  1024 B
    __shared__ __align__(16) float hpart[1024];             //  4096 B
    __shared__ __align__(16) unsigned short WU[9216];       // 18432 B: MLP weights

    const int tid = threadIdx.x, w = tid >> 6, lane = tid & 63;
    const int n = lane & 15, q = lane >> 4;
    const int bx = blockIdx.x;
    const int x0 = (bx % 12) * 4, y0 = ((bx / 12) % 12) * 4;
    const int T = bx / 144, d0 = T * 16;

    // ---- stage MLP weights (18 x 1024 B) via async global->LDS; done by [B1]
#pragma unroll
    for (int k = 0; k < 5; ++k) {
        int s = w + k * 4;
        if (s < 18)
            gll16(pk + 31744 + s * 512 + lane * 8, WU + s * 512);
    }

    // ---- stage conv3d patch via global_load_lds: idx -> LDS byte idx*16 (linear)
#pragma unroll
    for (int k = 0; k < 3; ++k) {
        int idx = tid + k * 256;                       // lane-varying
        unsigned short* dst = P + (k * 256 + w * 64) * 8;   // wave-uniform base
        if (idx < 588) {
            int row = idx >> 1, half = idx & 1;
            int py = row / 21, pz = row - py * 21;
            gll16(xhp + ((size_t)(d0 + pz) * 58 + (y0 + py)) * 64 + x0 + half * 8, dst);
        }
    }

    // ---- conv2d partials: wave w handles ic-groups c = 3w..3w+2 (3 indep chains)
    {
        const int pp = (y0 + (n >> 2)) * 50 + x0 + (n & 3);   // pos n = (yloc, xloc)
        const size_t bbase = (size_t)pp * 384 + q * 8;
        f32x4 hc[3];
#pragma unroll
        for (int cc = 0; cc < 3; ++cc) {
            const int c = w * 3 + cc;
            const unsigned short* ap = apack + ((size_t)(T * 12 + c) * 9) * 512 + lane * 8;
            const int coff = c * 32;
            f32x4 a0 = {0.f, 0.f, 0.f, 0.f};
#pragma unroll
            for (int t = 0; t < 9; ++t) {
                f16x8 a = *(const f16x8*)(ap + t * 512);
                const int dd = (t / 3) * 50 + (t % 3);        // compile-time
                f16x8 b = *(const f16x8*)(hyperTp + bbase + (size_t)dd * 384 + coff);
                a0 = __builtin_amdgcn_mfma_f32_16x16x32_f16(a, b, a0, 0, 0, 0);
            }
            hc[cc] = a0;
        }
#pragma unroll
        for (int e = 0; e < 4; ++e)
            hpart[w * 256 + (q * 4 + e) * 16 + n] = hc[0][e] + hc[1][e] + hc[2][e];
    }
    __syncthreads();   // [B1] patch + weights landed (vmcnt drained) + hpart done

    // ---- htile reduce: one (oc,pos) per thread; + b3 fold
    {
        const int oc = tid >> 4, pos = tid & 15;
        float h = b3[d0 + oc];
#pragma unroll
        for (int ww = 0; ww < 4; ++ww) h += hpart[ww * 256 + oc * 16 + pos];
        htile[oc * 16 + pos] = h;
    }

    // ---- conv3d main loop, fully unrolled (round-2 proven form)
    const f32x4 zf = {0.f, 0.f, 0.f, 0.f};
    f32x4 acc[4][2];
#pragma unroll
    for (int p = 0; p < 4; ++p) { acc[p][0] = zf; acc[p][1] = zf; }

    const f16x8* Av = (const f16x8*)pk;
    const int par = q >> 1;
    const unsigned short* Pb = P + (w * 21 + n) * 16 + (q & 1) * 8;
#pragma unroll
    for (int c = 0; c < 31; ++c) {
        const int r0 = 2 * c, r1 = 2 * c + 1;
        const int o0 = ((r0 % 11) * 21 + (r0 / 11)) * 16; // compile-time
        const int o1 = ((r1 % 11) * 21 + (r1 / 11)) * 16; // compile-time
        const unsigned short* rp = Pb + (par ? o1 : o0);
        unsigned int u[6];
        *(uint4*)&u[0] = *(const uint4*)rp;
        *(uint2*)&u[4] = *(const uint2*)(rp + 8);
        f16x8 ca0 = Av[c * 128 + lane];
        f16x8 ca1 = Av[c * 128 + 64 + lane];
#pragma unroll
        for (int px = 0; px < 4; ++px) {
            unsigned int bw[4];
#pragma unroll
            for (int i = 0; i < 4; ++i) {
                if ((px & 1) == 0) bw[i] = u[(px >> 1) + i];
                else bw[i] = (u[(px >> 1) + i] >> 16) | (u[(px >> 1) + 1 + i] << 16);
            }
            f16x8 bf = *(f16x8*)bw;
            acc[px][0] = __builtin_amdgcn_mfma_f32_16x16x32_f16(ca0, bf, acc[px][0], 0, 0, 0);
            acc[px][1] = __builtin_amdgcn_mfma_f32_16x16x32_f16(ca1, bf, acc[px][1], 0, 0, 0);
        }
    }
    __syncthreads();   // [B2] patch consumed; P becomes acc staging

    // ---- stage acc -> P as [64 pos][104]: pos row = w*16+n, 24 oc x 4 px
#pragma unroll
    for (int px = 0; px < 4; ++px) {
        unsigned int lo = pk2(acc[px][0][0], acc[px][0][1]);
        unsigned int hi = pk2(acc[px][0][2], acc[px][0][3]);
        *(uint2*)&P[(w * 16 + n) * 104 + px * 24 + q * 4] = make_uint2(lo, hi);
        if (q < 2) {
            unsigned int l2 = pk2(acc[px][1][0], acc[px][1][1]);
            unsigned int h2 = pk2(acc[px][1][2], acc[px][1][3]);
            *(uint2*)&P[(w * 16 + n) * 104 + px * 24 + 16 + q * 4] = make_uint2(l2, h2);
        }
    }
    // everything below is wave-local: LDS (b0/oacs/WU) + ds_bpermute, no barriers

    // ---- MLP: weights read from LDS (WU); redistribution via ds_bpermute
    const unsigned short* WaL = WU;            // 1536 shorts
    const unsigned short* WbL = WU + 1536;     // 6144 shorts
    const unsigned short* WcL = WU + 7680;     // 1536 shorts
    float bcv[4];
#pragma unroll
    for (int e = 0; e < 4; ++e) bcv[e] = (q * 4 + e < 9) ? bc[q * 4 + e] : 0.f;

    // bpermute lane indices: column group {n, n+16, n+32, n+48}, src q'' = (2q+g)&3
    const int idxg[2] = { (n + 16 * ((2 * q + 0) & 3)) * 4,
                          (n + 16 * ((2 * q + 1) & 3)) * 4 };
    const bool qlo = (q < 2);

    const f16x8 z8 = {};
    for (int px = 0; px < 4; ++px) {
        // ---- b0: 24 conv3d oc (+h, +1) from staging (wave-local)
        f16x8 b0;
        if (q < 3) {
            b0 = *(const f16x8*)&P[(w * 16 + n) * 104 + px * 24 + q * 8];
        } else {
            b0 = z8;
            b0[0] = (_Float16)htile[n * 16 + w * 4 + px];   // h feature (k=24)
            b0[1] = (_Float16)1.0f;                          // const (k=25)
        }
        // ---- layer a: 25(+h+const) -> 48, pack with relu
        unsigned int pw1[6];
#pragma unroll
        for (int s = 0; s < 3; ++s) {
            f16x8 a = *(const f16x8*)&WaL[(s * 64 + lane) * 8];
            f32x4 r1 = __builtin_amdgcn_mfma_f32_16x16x32_f16(a, b0, zf, 0, 0, 0);
            pw1[s * 2 + 0] = pkrtz(fmaxf(r1[0], 0.f), fmaxf(r1[1], 0.f));
            pw1[s * 2 + 1] = pkrtz(fmaxf(r1[2], 0.f), fmaxf(r1[3], 0.f));
        }
        // ---- a->b redistribution: 12 bpermutes (within 4-lane columns)
        unsigned int bpA[3][2][2];
#pragma unroll
        for (int s = 0; s < 3; ++s)
#pragma unroll
            for (int h = 0; h < 2; ++h) {
                bpA[s][h][0] = bperm(idxg[0], pw1[s * 2 + h]);
                bpA[s][h][1] = bperm(idxg[1], pw1[s * 2 + h]);
            }
        unsigned int bf0w[4], bf1w[4];
#pragma unroll
        for (int ww = 0; ww < 4; ++ww) {
            const int h = ww & 1, g = ww >> 1;
            bf0w[ww] = qlo ? bpA[0][h][g] : bpA[1][h][g];
            unsigned int c1 = (q == 2) ? ((ww == 0) ? 0x00003C00u : 0u) : 0u;
            bf1w[ww] = qlo ? bpA[2][h][g] : c1;
        }
        f16x8 bf0 = *(f16x8*)bf0w, bf1 = *(f16x8*)bf1w;
        // ---- layer b: 48(+const) -> 96, pack with relu
        unsigned int pw2[12];
#pragma unroll
        for (int s = 0; s < 6; ++s) {
            f16x8 a0w = *(const f16x8*)&WbL[((s * 2 + 0) * 64 + lane) * 8];
            f16x8 a1w = *(const f16x8*)&WbL[((s * 2 + 1) * 64 + lane) * 8];
            f32x4 rb = __builtin_amdgcn_mfma_f32_16x16x32_f16(a0w, bf0, zf, 0, 0, 0);
            rb = __builtin_amdgcn_mfma_f32_16x16x32_f16(a1w, bf1, rb, 0, 0, 0);
            pw2[s * 2 + 0] = pkrtz(fmaxf(rb[0], 0.f), fmaxf(rb[1], 0.f));
            pw2[s * 2 + 1] = pkrtz(fmaxf(rb[2], 0.f), fmaxf(rb[3], 0.f));
        }
        // ---- b->c redistribution (24 bpermutes) + layer c: 96 -> 9
        f32x4 rc = zf;
#pragma unroll
        for (int k3 = 0; k3 < 3; ++k3) {
            unsigned int wv[4];
#pragma unroll
            for (int ww = 0; ww < 4; ++ww) {
                const int h = ww & 1, g = ww >> 1;
                unsigned int lo_ = bperm(idxg[g], pw2[(2 * k3) * 2 + h]);
                unsigned int hi_ = bperm(idxg[g], pw2[(2 * k3 + 1) * 2 + h]);
                wv[ww] = qlo ? lo_ : hi_;
            }
            f16x8 bfc = *(f16x8*)wv;
            f16x8 aw = *(const f16x8*)&WcL[(k3 * 64 + lane) * 8];
            rc = __builtin_amdgcn_mfma_f32_16x16x32_f16(aw, bfc, rc, 0, 0, 0);
        }
        // ---- oacs: write into this px-group's (now dead) b0 segment of P
        {
            float* pr = (float*)(P + (w * 16 + n) * 104 + px * 24);
#pragma unroll
            for (int e = 0; e < 4; ++e) {
                const int row = q * 4 + e;
                if (row < 9) pr[row] = rc[e] + bcv[e];
            }
        }
    }

    // ---- likelihood: all 64 lanes, lane l -> pos (d = d0 + l>>2, y = y0+w, x = x0 + (l&3))
    {
        const float* pr = (const float*)(P + (w * 16 + (lane >> 2)) * 104 + (lane & 3) * 24);
        f32x4 oA = *(const f32x4*)pr;
        f32x4 oB = *(const f32x4*)(pr + 4);
        float o8 = pr[8];
        const int gp = (d0 + (lane >> 2)) * HW + (y0 + w) * 48 + x0 + (lane & 3);
        const float xv = xg[gp];
        float m = fmaxf(oB[2], fmaxf(oB[3], o8));
        float e0 = expf(oB[2] - m), e1 = expf(oB[3] - m), e2 = expf(o8 - m);
        float inv_es = 1.0f / (e0 + e1 + e2);
        float mu0 = oA[0], mu1 = oA[1], mu2 = oA[2];
        float s0 = oA[3], s1 = oB[0], s2 = oB[1];
        float p = 0.f;
#pragma unroll
        for (int jj = 0; jj < 3; ++jj) {
            float mu = (jj == 0) ? mu0 : (jj == 1) ? mu1 : mu2;
            float sc = (jj == 0) ? s0 : (jj == 1) ? s1 : s2;
            sc = (sc == 0.0f) ? 1e-9f : sc;
            sc = fabsf(sc);
            float a = phi_f((xv + 0.5f - mu) / sc);
            float b = phi_f((xv - 0.5f - mu) / sc);
            float lik = fabsf(a - b);
            float wgt = ((jj == 0) ? e0 : (jj == 1) ? e1 : e2) * inv_es;
            p = fmaf(wgt, lik, p);
        }
        out[gp] = p;
        out[NPOS + (size_t)0 * NPOS + gp] = mu0;
        out[NPOS + (size_t)1 * NPOS + gp] = mu1;
        out[NPOS + (size_t)2 * NPOS + gp] = mu2;
        out[NPOS + (size_t)3 * NPOS + gp] = s0;
        out[NPOS + (size_t)4 * NPOS + gp] = s1;
        out[NPOS + (size_t)5 * NPOS + gp] = s2;
        out[NPOS + (size_t)6 * NPOS + gp] = oB[2];
        out[NPOS + (size_t)7 * NPOS + gp] = oB[3];
        out[NPOS + (size_t)8 * NPOS + gp] = o8;
    }
}

extern "C" void kernel_launch(void* const* d_in, const int* in_sizes, int n_in,
                              void* d_out, int out_size, void* d_ws, size_t ws_size,
                              hipStream_t stream) {
    const float* x     = (const float*)d_in[0];
    const float* hyper = (const float*)d_in[1];
    const float* W3    = (const float*)d_in[2];
    const float* b3    = (const float*)d_in[3];
    const float* W1    = (const float*)d_in[4];
    const float* b1    = (const float*)d_in[5];
    const float* Wa    = (const float*)d_in[6];
    const float* ba    = (const float*)d_in[7];
    const float* Wb    = (const float*)d_in[8];
    const float* bb    = (const float*)d_in[9];
    const float* Wc    = (const float*)d_in[10];
    const float* bc    = (const float*)d_in[11];
    float* out = (float*)d_out;

    unsigned short* hyperTp = (unsigned short*)d_ws;           // 960000 f16
    unsigned short* apack   = hyperTp + 960000;                // 663552 f16
    unsigned short* pk      = apack + 663552;                  // 40960 f16
    unsigned short* xhp     = pk + 40960;                      // 749824 f16 (padded x)

    prep_all<<<1985, 256, 0, stream>>>(hyper, W3, W1, Wa, ba, b1, Wb, bb, Wc, x,
                                       hyperTp, apack, pk, xhp);
    fused3<<<1728, 256, 0, stream>>>(xhp, pk, hyperTp, apack, b3, x, bc, out);
}